// Round 8
// baseline (120.457 us; speedup 1.0000x reference)
//
#include <hip/hip_runtime.h>

namespace {

typedef float v2f __attribute__((ext_vector_type(2)));

constexpr int LMAX  = 10;
constexpr int NPART = 4;
// Register-balanced 4-way partition: packed (2-point) accumulators cost 2
// VGPRs per slot, so parts are sized to keep live state well under the cap:
// P0{3,10}=34 acc, P1{2,4,9}=40, P2{1,5,8}=37, P3{0,6,7}=35.
constexpr int PART_OF_L[LMAX + 1] = {3, 2, 1, 0, 1, 2, 3, 3, 2, 1, 0};
constexpr double PI_D = 3.14159265358979323846;

constexpr double dfact(int n) {
    double r = 1.0;
    for (int i = 2; i <= n; ++i) r *= (double)i;
    return r;
}

constexpr double csqrt(double x) {
    if (x <= 0.0) return 0.0;
    double g = x > 1.0 ? x : 1.0;
    for (int i = 0; i < 100; ++i) g = 0.5 * (g + x / g);
    return g;
}

constexpr double FACT[LMAX + 1] = {1., 1., 2., 6., 24., 120., 720., 5040., 40320., 362880., 3628800.};

// ---- global moment layout in workspace (same as R6/R7) --------------------
//   clm_r(l,m) = scale * sum_q c(l,m,q) * (M_{q+m,l} - N_{q,l})
//   M_{p,l} = sum_pts Re(z1^p)^2 * w0 * r^l     (66 entries)
//   N_{q,l} = sum_pts Im(z1^q)^2 * w0 * r^l     (25 entries, q>=1)
constexpr int NM_M = 66;
constexpr int mi(int p, int l) { return l * (l + 1) / 2 + p; }
constexpr int ni_base(int l) {
    int c = 0;
    for (int ll = 0; ll < l; ++ll) c += ll / 2;
    return c;
}
constexpr int ni(int q, int l) { return NM_M + ni_base(l) + (q - 1); }
constexpr int NM_N  = 25;
constexpr int NMOM  = NM_M + NM_N;   // 91
constexpr int ZSLOT = NMOM;          // always-zero ws slot
constexpr int WS_FLOATS = NMOM + 1;  // 92

// ---- per-part helpers ------------------------------------------------------
constexpr int part_lmax(int part) {
    int mx = 0;
    for (int l = 0; l <= LMAX; ++l)
        if (PART_OF_L[l] == part) mx = l;
    return mx;
}
constexpr int nls(int part) {
    int c = 0;
    for (int l = 0; l <= LMAX; ++l)
        if (PART_OF_L[l] == part) ++c;
    return c;
}
constexpr int lidx(int part, int l) {
    int c = 0;
    for (int ll = 0; ll < l; ++ll)
        if (PART_OF_L[ll] == part) ++c;
    return c;
}
constexpr int part_ls(int part, int k) {
    int c = 0;
    for (int l = 0; l <= LMAX; ++l)
        if (PART_OF_L[l] == part) {
            if (c == k) return l;
            ++c;
        }
    return -1;
}
constexpr int nM(int part) {
    int c = 0;
    for (int l = 0; l <= LMAX; ++l)
        if (PART_OF_L[l] == part) c += l + 1;
    return c;
}
constexpr int nN(int part) {
    int c = 0;
    for (int l = 0; l <= LMAX; ++l)
        if (PART_OF_L[l] == part) c += l / 2;
    return c;
}
constexpr int nMom(int part) { return nM(part) + nN(part); }
constexpr int nI(int part) {
    int c = 0;
    for (int l = 0; l <= LMAX; ++l)
        if (PART_OF_L[l] == part) c += l;
    return c;
}
constexpr int nAcc(int part) { return nMom(part) + nI(part); }

constexpr int locM(int part, int p, int l) {
    int c = 0;
    for (int ll = 0; ll < l; ++ll)
        if (PART_OF_L[ll] == part) c += ll + 1;
    return c + p;
}
constexpr int locN(int part, int q, int l) {
    int c = nM(part);
    for (int ll = 0; ll < l; ++ll)
        if (PART_OF_L[ll] == part) c += ll / 2;
    return c + (q - 1);
}
constexpr int locI(int part, int m, int l) {
    int c = nMom(part);
    for (int ll = 0; ll < l; ++ll)
        if (PART_OF_L[ll] == part) c += ll;
    return c + (m - 1);
}

constexpr int MAXMOM = 25;  // P1: 18 M + 7 N
constexpr int MAXIMG = 15;  // P1

// Horner coefficient for the collapsed imag sum: (-1)^q / ((q+m)! q! (l-m-2q)!)
constexpr float ci_coef(int l, int m, int q) {
    const double c = 1.0 / (FACT[q + m] * FACT[q] * FACT[l - m - 2 * q]);
    return (q & 1) ? (float)(-c) : (float)c;
}

struct PartTab {
    short wsmap[NPART][MAXMOM];  // local moment slot -> global ws index
    int   omap[NPART][MAXIMG];   // local imag slot -> out index
    float oscl[NPART][MAXIMG];   // imag output scale (sqrt2*(-1)^m, T==1 fold)
};

constexpr PartTab make_pt() {
    PartTab t{};
    for (int part = 0; part < NPART; ++part) {
        for (int l = 0; l <= LMAX; ++l) {
            if (PART_OF_L[l] != part) continue;
            for (int p = 0; p <= l; ++p) t.wsmap[part][locM(part, p, l)] = (short)mi(p, l);
            for (int q = 1; q <= l / 2; ++q) t.wsmap[part][locN(part, q, l)] = (short)ni(q, l);
            for (int m = 1; m <= l; ++m) {
                const int    k     = locI(part, m, l) - nMom(part);
                const double scale = csqrt(dfact(l + m) * dfact(l - m)) * csqrt((2 * l + 1) / (4.0 * PI_D));
                const double f     = csqrt(2.0) * ((m & 1) ? -1.0 : 1.0);
                const double fold  = ((l - m) <= 1) ? 1.0 / (dfact(m) * dfact(l - m)) : 1.0;
                t.omap[part][k] = l * l + l - m;
                t.oscl[part][k] = (float)(f * scale * fold);
            }
        }
    }
    return t;
}

// Combine-kernel table: per real output slot, the q-term list over moments.
struct CombTab {
    int   out[66];
    float scale[66];
    int   nt[66];
    float c[66][6];
    short mIx[66][6];
    short nIx[66][6];
};

constexpr CombTab make_comb() {
    CombTab t{};
    int k = 0;
    for (int l = 0; l <= LMAX; ++l) {
        for (int m = 0; m <= l; ++m) {
            const double scale = csqrt(dfact(l + m) * dfact(l - m)) * csqrt((2 * l + 1) / (4.0 * PI_D));
            const double f     = (m == 0) ? 1.0 : csqrt(2.0) * ((m & 1) ? -1.0 : 1.0);
            t.out[k]   = (m == 0) ? l * l + l : l * l + l + m;
            t.scale[k] = (float)(f * scale);
            const int Q = (l - m) / 2;
            t.nt[k]     = Q + 1;
            for (int q = 0; q <= Q; ++q) {
                const double c = 1.0 / (FACT[q + m] * FACT[q] * FACT[l - m - 2 * q]);
                t.c[k][q]   = (float)c;
                t.mIx[k][q] = (short)mi(q + m, l);
                t.nIx[k][q] = (short)(q >= 1 ? ni(q, l) : ZSLOT);
            }
            ++k;
        }
    }
    return t;
}

__constant__ PartTab c_pt = make_pt();
__constant__ CombTab c_cb = make_comb();

// Load the point pair {2*ip, 2*ip+1} into packed X/Y/Z (point j in lane j).
// OOB points zero-fill; zero points contribute exactly zero (w0 = 0).
__device__ __forceinline__ void load_pair(const float* __restrict__ pos, int ip, int n,
                                          v2f& X, v2f& Y, v2f& Z) {
    const int i0 = 2 * ip;
    if (i0 + 1 < n) {
        const float2* p2 = reinterpret_cast<const float2*>(pos + 3 * i0);
        const float2  a = p2[0], b = p2[1], d = p2[2];
        X.x = a.x; X.y = b.y;
        Y.x = a.y; Y.y = d.x;
        Z.x = b.x; Z.y = d.y;
    } else if (i0 < n) {
        X.x = pos[3 * i0]; Y.x = pos[3 * i0 + 1]; Z.x = pos[3 * i0 + 2];
        X.y = 0.f; Y.y = 0.f; Z.y = 0.f;
    } else {
        X = (v2f)(0.f); Y = (v2f)(0.f); Z = (v2f)(0.f);
    }
}

}  // namespace

// R7 chassis (moment factorization + packed v_pk_* FP32, 4 parts) with two
// stall-fraction fixes driven by R7 counters (VALUBusy 45%, Occupancy 21%):
//  1. 6 blocks/CU (was 3): average resident waves/SIMD was only ~1.7 —
//     ramp/tail/part-imbalance starved the SIMDs.  Finer grain + more waves.
//     (R3's "more waves didn't help" was a different regime: its epilogue was
//     ~20% of per-thread work; here it's ~8%.)
//  2. Even/odd z-power chains: the 10-deep serial complex-multiply recurrence
//     becomes two independent 5-deep chains advanced by z^2 — same op count,
//     2x ILP in the main loop's only long dependency chain.
template <int PART>
__device__ __forceinline__ void sht_part(const float* __restrict__ pos, float* __restrict__ out,
                                         float* __restrict__ ws, int n, int nblk) {
    constexpr int PL  = part_lmax(PART);
    constexpr int QX  = PL / 2;
    constexpr int NL  = nls(PART);
    constexpr int NMO = nMom(PART);
    constexpr int NAC = nAcc(PART);

    v2f acc[NAC];
#pragma unroll
    for (int k = 0; k < NAC; ++k) acc[k] = (v2f)(0.f);

    const int bid    = (int)(blockIdx.x >> 2);
    const int tid    = bid * 256 + (int)threadIdx.x;
    const int stride = nblk * 256;  // in pairs
    const int npair  = (n + 1) >> 1;

    v2f X, Y, Z;
    int ip = tid;
    load_pair(pos, ip, n, X, Y, Z);

    while (ip < npair) {
        // software-pipelined prefetch of the next pair
        const int inext = ip + stride;
        v2f       nX, nY, nZ;
        load_pair(pos, inext, n, nX, nY, nZ);

        const v2f r2 = X * X + Y * Y + Z * Z;
        v2f       nrm;
        nrm.x = sqrtf(r2.x);
        nrm.y = sqrtf(r2.y);
        v2f w0;
        w0.x = (nrm.x > 0.f) ? Z.x : 0.f;  // x0 * mask
        w0.y = (nrm.y > 0.f) ? Z.y : 0.f;

        const v2f ar  = -0.5f * X;
        const v2f ai  = -0.5f * Y;
        const v2f rho = ar * ar + ai * ai;  // |z1|^2

        // wl[k] = w0 * nrm^l via binary decomposition (parts mix parities).
        v2f wl[NL];
        {
            const v2f p2v = nrm * nrm;
            const v2f p4v = p2v * p2v;
            const v2f p8v = p4v * p4v;
#pragma unroll
            for (int k = 0; k < NL; ++k) {
                const int l = part_ls(PART, k);  // compile-time
                v2f       t = w0;
                if (l & 1) t = t * nrm;
                if (l & 2) t = t * p2v;
                if (l & 4) t = t * p4v;
                if (l & 8) t = t * p8v;
                wl[k] = t;
            }
        }

        // p-major powers of z1 via TWO independent even/odd chains advanced
        // by z^2 (dep depth PL/2 instead of PL); sr_p/si_p consumed
        // immediately into moment accumulators; only zi[] is tabled.
        v2f zi[PL + 1];
        v2f pr[2], pim[2];
        pr[0]  = (v2f)(1.f);
        pim[0] = (v2f)(0.f);
        pr[1]  = ar;
        pim[1] = ai;
        const v2f z2r = ar * ar - ai * ai;
        const v2f z2i = 2.f * (ar * ai);
#pragma unroll
        for (int p = 0; p <= PL; ++p) {
            const int par = p & 1;  // compile-time under full unroll
            if (p >= 2) {
                const v2f nr = z2r * pr[par] - z2i * pim[par];
                pim[par]     = z2r * pim[par] + z2i * pr[par];
                pr[par]      = nr;
            }
            zi[p] = pim[par];
            const v2f srp = pr[par] * pr[par];
#pragma unroll
            for (int l = 0; l <= LMAX; ++l)
                if (PART_OF_L[l] == PART && l >= p)
                    acc[locM(PART, p, l)] += srp * wl[lidx(PART, l)];
            if (p >= 1 && p <= QX) {
                const v2f sip = pim[par] * pim[par];
#pragma unroll
                for (int l = 0; l <= LMAX; ++l)
                    if (PART_OF_L[l] == PART && l >= 2 * p)
                        acc[locN(PART, p, l)] += sip * wl[lidx(PART, l)];
            }
        }

        // imag pass: acc_I(l,m) += zi[m] * Horner_q(+-c * rho^q) * wrl
#pragma unroll
        for (int l = 0; l <= LMAX; ++l) {
            if (PART_OF_L[l] != PART) continue;
            const v2f wrl = wl[lidx(PART, l)];
#pragma unroll
            for (int m = 1; m <= l; ++m) {
                const int Q = (l - m) >> 1;
                if (Q == 0) {
                    acc[locI(PART, m, l)] += zi[m] * wrl;  // coeff folded into oscl
                } else {
                    v2f tq = (v2f)(ci_coef(l, m, Q));
#pragma unroll
                    for (int q = Q - 1; q >= 0; --q) tq = tq * rho + ci_coef(l, m, q);
                    acc[locI(PART, m, l)] += (tq * zi[m]) * wrl;
                }
            }
        }

        ip = inext;
        X  = nX;
        Y  = nY;
        Z  = nZ;
    }

    // Fold packed lanes, then wave shuffle reduction, then cross-wave via LDS.
    __shared__ float red[4][NAC];
    const int lane = threadIdx.x & 63;
    const int wav  = threadIdx.x >> 6;
#pragma unroll
    for (int k = 0; k < NAC; ++k) {
        float v = acc[k].x + acc[k].y;
#pragma unroll
        for (int off = 32; off > 0; off >>= 1) v += __shfl_down(v, off, 64);
        if (lane == 0) red[wav][k] = v;
    }
    __syncthreads();
    if ((int)threadIdx.x < NAC) {
        const int   k = (int)threadIdx.x;
        const float v = red[0][k] + red[1][k] + red[2][k] + red[3][k];
        if (k < NMO) {
            atomicAdd(&ws[c_pt.wsmap[PART][k]], v);
        } else {
            const int j = k - NMO;
            atomicAdd(&out[c_pt.omap[PART][j]], v * c_pt.oscl[PART][j]);
        }
    }
}

__global__ __launch_bounds__(256, 3) void sht_kernel(const float* __restrict__ pos,
                                                     float* __restrict__ out,
                                                     float* __restrict__ ws, int n, int nblk) {
    // part = blockIdx & 3: stride-256 round-robin (256 % 4 == 0) keeps all
    // resident blocks on a CU in the same part -> I$ locality.
    switch (blockIdx.x & 3) {
        case 0: sht_part<0>(pos, out, ws, n, nblk); break;
        case 1: sht_part<1>(pos, out, ws, n, nblk); break;
        case 2: sht_part<2>(pos, out, ws, n, nblk); break;
        default: sht_part<3>(pos, out, ws, n, nblk); break;
    }
}

// Tiny in-stream combine: real outputs from moments.  Writes only real slots,
// disjoint from the imag atomics' targets; stream order puts it after.
__global__ void sht_combine(const float* __restrict__ ws, float* __restrict__ out) {
    const int t = (int)threadIdx.x;
    if (t < 66) {
        const int nt = c_cb.nt[t];
        float     v  = 0.f;
        for (int j = 0; j < nt; ++j)
            v += c_cb.c[t][j] * (ws[c_cb.mIx[t][j]] - ws[c_cb.nIx[t][j]]);
        out[c_cb.out[t]] = c_cb.scale[t] * v;
    }
}

extern "C" void kernel_launch(void* const* d_in, const int* in_sizes, int n_in,
                              void* d_out, int out_size, void* d_ws, size_t ws_size,
                              hipStream_t stream) {
    const float* pos = (const float*)d_in[0];
    float* out       = (float*)d_out;
    float* ws        = (float*)d_ws;
    const int n      = in_sizes[0] / 3;  // (N,3) flat -> N points

    // d_out is poisoned before every launch; ws holds the moment accumulators.
    hipMemsetAsync(d_out, 0, (size_t)out_size * sizeof(float), stream);
    hipMemsetAsync(d_ws, 0, WS_FLOATS * sizeof(float), stream);

    const int threads = 256;
    // 384 blocks/part x 4 parts = 1536 = 6 blocks/CU.  R7 measured average
    // occupancy of only ~1.7 waves/SIMD at 3 blocks/CU (ramp/tail/imbalance);
    // ~10 pairs/thread keeps the <=40-slot epilogue at ~8% of per-wave work.
    const int nblk_per_part = 384;
    const int blocks        = NPART * nblk_per_part;  // 1536
    sht_kernel<<<blocks, threads, 0, stream>>>(pos, out, ws, n, nblk_per_part);
    sht_combine<<<1, 128, 0, stream>>>(ws, out);
}

// Round 9
// 108.829 us; speedup vs baseline: 1.1069x; 1.1069x over previous
//
#include <hip/hip_runtime.h>

namespace {

typedef float v2f __attribute__((ext_vector_type(2)));

constexpr int LMAX  = 10;
constexpr int NPART = 4;
// Register-balanced 4-way partition: packed (2-point) accumulators cost 2
// VGPRs per slot, so parts are sized to keep live state under the (256,3)
// cap of 170: P0{3,10}=34 acc, P1{2,4,9}=40, P2{1,5,8}=37, P3{0,6,7}=35.
constexpr int PART_OF_L[LMAX + 1] = {3, 2, 1, 0, 1, 2, 3, 3, 2, 1, 0};
constexpr double PI_D = 3.14159265358979323846;

constexpr double dfact(int n) {
    double r = 1.0;
    for (int i = 2; i <= n; ++i) r *= (double)i;
    return r;
}

constexpr double csqrt(double x) {
    if (x <= 0.0) return 0.0;
    double g = x > 1.0 ? x : 1.0;
    for (int i = 0; i < 100; ++i) g = 0.5 * (g + x / g);
    return g;
}

constexpr double FACT[LMAX + 1] = {1., 1., 2., 6., 24., 120., 720., 5040., 40320., 362880., 3628800.};

// ---- global moment layout in workspace (same as R6/R7) --------------------
//   clm_r(l,m) = scale * sum_q c(l,m,q) * (M_{q+m,l} - N_{q,l})
//   M_{p,l} = sum_pts Re(z1^p)^2 * w0 * r^l     (66 entries)
//   N_{q,l} = sum_pts Im(z1^q)^2 * w0 * r^l     (25 entries, q>=1)
constexpr int NM_M = 66;
constexpr int mi(int p, int l) { return l * (l + 1) / 2 + p; }
constexpr int ni_base(int l) {
    int c = 0;
    for (int ll = 0; ll < l; ++ll) c += ll / 2;
    return c;
}
constexpr int ni(int q, int l) { return NM_M + ni_base(l) + (q - 1); }
constexpr int NM_N  = 25;
constexpr int NMOM  = NM_M + NM_N;   // 91
constexpr int ZSLOT = NMOM;          // always-zero ws slot
constexpr int WS_FLOATS = NMOM + 1;  // 92

// ---- per-part helpers ------------------------------------------------------
constexpr int part_lmax(int part) {
    int mx = 0;
    for (int l = 0; l <= LMAX; ++l)
        if (PART_OF_L[l] == part) mx = l;
    return mx;
}
constexpr int nls(int part) {
    int c = 0;
    for (int l = 0; l <= LMAX; ++l)
        if (PART_OF_L[l] == part) ++c;
    return c;
}
constexpr int lidx(int part, int l) {
    int c = 0;
    for (int ll = 0; ll < l; ++ll)
        if (PART_OF_L[ll] == part) ++c;
    return c;
}
constexpr int part_ls(int part, int k) {
    int c = 0;
    for (int l = 0; l <= LMAX; ++l)
        if (PART_OF_L[l] == part) {
            if (c == k) return l;
            ++c;
        }
    return -1;
}
constexpr int nM(int part) {
    int c = 0;
    for (int l = 0; l <= LMAX; ++l)
        if (PART_OF_L[l] == part) c += l + 1;
    return c;
}
constexpr int nN(int part) {
    int c = 0;
    for (int l = 0; l <= LMAX; ++l)
        if (PART_OF_L[l] == part) c += l / 2;
    return c;
}
constexpr int nMom(int part) { return nM(part) + nN(part); }
constexpr int nI(int part) {
    int c = 0;
    for (int l = 0; l <= LMAX; ++l)
        if (PART_OF_L[l] == part) c += l;
    return c;
}
constexpr int nAcc(int part) { return nMom(part) + nI(part); }

constexpr int locM(int part, int p, int l) {
    int c = 0;
    for (int ll = 0; ll < l; ++ll)
        if (PART_OF_L[ll] == part) c += ll + 1;
    return c + p;
}
constexpr int locN(int part, int q, int l) {
    int c = nM(part);
    for (int ll = 0; ll < l; ++ll)
        if (PART_OF_L[ll] == part) c += ll / 2;
    return c + (q - 1);
}
constexpr int locI(int part, int m, int l) {
    int c = nMom(part);
    for (int ll = 0; ll < l; ++ll)
        if (PART_OF_L[ll] == part) c += ll;
    return c + (m - 1);
}

constexpr int MAXMOM = 25;  // P1: 18 M + 7 N
constexpr int MAXIMG = 15;  // P1

// Horner coefficient for the collapsed imag sum: (-1)^q / ((q+m)! q! (l-m-2q)!)
constexpr float ci_coef(int l, int m, int q) {
    const double c = 1.0 / (FACT[q + m] * FACT[q] * FACT[l - m - 2 * q]);
    return (q & 1) ? (float)(-c) : (float)c;
}

struct PartTab {
    short wsmap[NPART][MAXMOM];  // local moment slot -> global ws index
    int   omap[NPART][MAXIMG];   // local imag slot -> out index
    float oscl[NPART][MAXIMG];   // imag output scale (sqrt2*(-1)^m, T==1 fold)
};

constexpr PartTab make_pt() {
    PartTab t{};
    for (int part = 0; part < NPART; ++part) {
        for (int l = 0; l <= LMAX; ++l) {
            if (PART_OF_L[l] != part) continue;
            for (int p = 0; p <= l; ++p) t.wsmap[part][locM(part, p, l)] = (short)mi(p, l);
            for (int q = 1; q <= l / 2; ++q) t.wsmap[part][locN(part, q, l)] = (short)ni(q, l);
            for (int m = 1; m <= l; ++m) {
                const int    k     = locI(part, m, l) - nMom(part);
                const double scale = csqrt(dfact(l + m) * dfact(l - m)) * csqrt((2 * l + 1) / (4.0 * PI_D));
                const double f     = csqrt(2.0) * ((m & 1) ? -1.0 : 1.0);
                const double fold  = ((l - m) <= 1) ? 1.0 / (dfact(m) * dfact(l - m)) : 1.0;
                t.omap[part][k] = l * l + l - m;
                t.oscl[part][k] = (float)(f * scale * fold);
            }
        }
    }
    return t;
}

// Combine-kernel table: per real output slot, the q-term list over moments.
struct CombTab {
    int   out[66];
    float scale[66];
    int   nt[66];
    float c[66][6];
    short mIx[66][6];
    short nIx[66][6];
};

constexpr CombTab make_comb() {
    CombTab t{};
    int k = 0;
    for (int l = 0; l <= LMAX; ++l) {
        for (int m = 0; m <= l; ++m) {
            const double scale = csqrt(dfact(l + m) * dfact(l - m)) * csqrt((2 * l + 1) / (4.0 * PI_D));
            const double f     = (m == 0) ? 1.0 : csqrt(2.0) * ((m & 1) ? -1.0 : 1.0);
            t.out[k]   = (m == 0) ? l * l + l : l * l + l + m;
            t.scale[k] = (float)(f * scale);
            const int Q = (l - m) / 2;
            t.nt[k]     = Q + 1;
            for (int q = 0; q <= Q; ++q) {
                const double c = 1.0 / (FACT[q + m] * FACT[q] * FACT[l - m - 2 * q]);
                t.c[k][q]   = (float)c;
                t.mIx[k][q] = (short)mi(q + m, l);
                t.nIx[k][q] = (short)(q >= 1 ? ni(q, l) : ZSLOT);
            }
            ++k;
        }
    }
    return t;
}

__constant__ PartTab c_pt = make_pt();
__constant__ CombTab c_cb = make_comb();

// Packed accumulate d += a*b, forced to (a) the v_pk_fma_f32 encoding and
// (b) an ARCH-VGPR destination via the "+v" constraint.  R7/R8 counters
// (VGPR_Count=64 against 80+ regs of live accumulator state, no scratch)
// showed the compiler parks acc arrays in AGPRs and pays a move tax on
// every touch (~387 measured vs ~160 static instr/pair·part).  Pinning each
// accumulate to a VGPR-constrained asm makes AGPR residency useless to the
// allocator, so the acc array stays in VGPRs: 1 instr per touch.
__device__ __forceinline__ void pk_fma(v2f& d, v2f a, v2f b) {
    asm("v_pk_fma_f32 %0, %1, %2, %0" : "+v"(d) : "v"(a), "v"(b));
}

// Load the point pair {2*ip, 2*ip+1} into packed X/Y/Z (point j in lane j).
// OOB points zero-fill; zero points contribute exactly zero (w0 = 0).
__device__ __forceinline__ void load_pair(const float* __restrict__ pos, int ip, int n,
                                          v2f& X, v2f& Y, v2f& Z) {
    const int i0 = 2 * ip;
    if (i0 + 1 < n) {
        const float2* p2 = reinterpret_cast<const float2*>(pos + 3 * i0);
        const float2  a = p2[0], b = p2[1], d = p2[2];
        X.x = a.x; X.y = b.y;
        Y.x = a.y; Y.y = d.x;
        Z.x = b.x; Z.y = d.y;
    } else if (i0 < n) {
        X.x = pos[3 * i0]; Y.x = pos[3 * i0 + 1]; Z.x = pos[3 * i0 + 2];
        X.y = 0.f; Y.y = 0.f; Z.y = 0.f;
    } else {
        X = (v2f)(0.f); Y = (v2f)(0.f); Z = (v2f)(0.f);
    }
}

}  // namespace

// R7 chassis exactly (moment factorization + packed math, 4 parts, serial
// z-power chain, 3 blocks/CU — R8 proved 6 blocks/CU + even/odd chains both
// regress), plus the pk_fma VGPR pin on every accumulator touch.
template <int PART>
__device__ __forceinline__ void sht_part(const float* __restrict__ pos, float* __restrict__ out,
                                         float* __restrict__ ws, int n, int nblk) {
    constexpr int PL  = part_lmax(PART);
    constexpr int QX  = PL / 2;
    constexpr int NL  = nls(PART);
    constexpr int NMO = nMom(PART);
    constexpr int NAC = nAcc(PART);

    v2f acc[NAC];
#pragma unroll
    for (int k = 0; k < NAC; ++k) acc[k] = (v2f)(0.f);

    const int bid    = (int)(blockIdx.x >> 2);
    const int tid    = bid * 256 + (int)threadIdx.x;
    const int stride = nblk * 256;  // in pairs
    const int npair  = (n + 1) >> 1;

    v2f X, Y, Z;
    int ip = tid;
    load_pair(pos, ip, n, X, Y, Z);

    while (ip < npair) {
        // software-pipelined prefetch of the next pair
        const int inext = ip + stride;
        v2f       nX, nY, nZ;
        load_pair(pos, inext, n, nX, nY, nZ);

        const v2f r2 = X * X + Y * Y + Z * Z;
        v2f       nrm;
        nrm.x = sqrtf(r2.x);
        nrm.y = sqrtf(r2.y);
        v2f w0;
        w0.x = (nrm.x > 0.f) ? Z.x : 0.f;  // x0 * mask
        w0.y = (nrm.y > 0.f) ? Z.y : 0.f;

        const v2f ar  = -0.5f * X;
        const v2f ai  = -0.5f * Y;
        const v2f rho = ar * ar + ai * ai;  // |z1|^2

        // wl[k] = w0 * nrm^l via binary decomposition (parts mix parities).
        v2f wl[NL];
        {
            const v2f p2v = nrm * nrm;
            const v2f p4v = p2v * p2v;
            const v2f p8v = p4v * p4v;
#pragma unroll
            for (int k = 0; k < NL; ++k) {
                const int l = part_ls(PART, k);  // compile-time
                v2f       t = w0;
                if (l & 1) t = t * nrm;
                if (l & 2) t = t * p2v;
                if (l & 4) t = t * p4v;
                if (l & 8) t = t * p8v;
                wl[k] = t;
            }
        }

        // p-major rolling powers of z1: consume sr_p/si_p immediately into
        // moment accumulators; only zi[] is tabled (needed by imag pass).
        v2f zi[PL + 1];
        v2f zrc = (v2f)(1.f), zic = (v2f)(0.f);
#pragma unroll
        for (int p = 0; p <= PL; ++p) {
            if (p) {
                const v2f nr = ar * zrc - ai * zic;
                zic          = ar * zic + ai * zrc;
                zrc          = nr;
            }
            zi[p] = zic;
            const v2f srp = zrc * zrc;
#pragma unroll
            for (int l = 0; l <= LMAX; ++l)
                if (PART_OF_L[l] == PART && l >= p)
                    pk_fma(acc[locM(PART, p, l)], srp, wl[lidx(PART, l)]);
            if (p >= 1 && p <= QX) {
                const v2f sip = zic * zic;
#pragma unroll
                for (int l = 0; l <= LMAX; ++l)
                    if (PART_OF_L[l] == PART && l >= 2 * p)
                        pk_fma(acc[locN(PART, p, l)], sip, wl[lidx(PART, l)]);
            }
        }

        // imag pass: acc_I(l,m) += zi[m] * Horner_q(+-c * rho^q) * wrl
#pragma unroll
        for (int l = 0; l <= LMAX; ++l) {
            if (PART_OF_L[l] != PART) continue;
            const v2f wrl = wl[lidx(PART, l)];
#pragma unroll
            for (int m = 1; m <= l; ++m) {
                const int Q = (l - m) >> 1;
                if (Q == 0) {
                    pk_fma(acc[locI(PART, m, l)], zi[m], wrl);  // coeff in oscl
                } else {
                    v2f tq = (v2f)(ci_coef(l, m, Q));
#pragma unroll
                    for (int q = Q - 1; q >= 0; --q) tq = tq * rho + ci_coef(l, m, q);
                    pk_fma(acc[locI(PART, m, l)], tq * zi[m], wrl);
                }
            }
        }

        ip = inext;
        X  = nX;
        Y  = nY;
        Z  = nZ;
    }

    // Fold packed lanes, then wave shuffle reduction, then cross-wave via LDS.
    __shared__ float red[4][NAC];
    const int lane = threadIdx.x & 63;
    const int wav  = threadIdx.x >> 6;
#pragma unroll
    for (int k = 0; k < NAC; ++k) {
        float v = acc[k].x + acc[k].y;
#pragma unroll
        for (int off = 32; off > 0; off >>= 1) v += __shfl_down(v, off, 64);
        if (lane == 0) red[wav][k] = v;
    }
    __syncthreads();
    if ((int)threadIdx.x < NAC) {
        const int   k = (int)threadIdx.x;
        const float v = red[0][k] + red[1][k] + red[2][k] + red[3][k];
        if (k < NMO) {
            atomicAdd(&ws[c_pt.wsmap[PART][k]], v);
        } else {
            const int j = k - NMO;
            atomicAdd(&out[c_pt.omap[PART][j]], v * c_pt.oscl[PART][j]);
        }
    }
}

__global__ __launch_bounds__(256, 3) void sht_kernel(const float* __restrict__ pos,
                                                     float* __restrict__ out,
                                                     float* __restrict__ ws, int n, int nblk) {
    // part = blockIdx & 3: stride-256 round-robin (256 % 4 == 0) keeps all
    // resident blocks on a CU in the same part -> I$ locality.
    switch (blockIdx.x & 3) {
        case 0: sht_part<0>(pos, out, ws, n, nblk); break;
        case 1: sht_part<1>(pos, out, ws, n, nblk); break;
        case 2: sht_part<2>(pos, out, ws, n, nblk); break;
        default: sht_part<3>(pos, out, ws, n, nblk); break;
    }
}

// Tiny in-stream combine: real outputs from moments.  Writes only real slots,
// disjoint from the imag atomics' targets; stream order puts it after.
__global__ void sht_combine(const float* __restrict__ ws, float* __restrict__ out) {
    const int t = (int)threadIdx.x;
    if (t < 66) {
        const int nt = c_cb.nt[t];
        float     v  = 0.f;
        for (int j = 0; j < nt; ++j)
            v += c_cb.c[t][j] * (ws[c_cb.mIx[t][j]] - ws[c_cb.nIx[t][j]]);
        out[c_cb.out[t]] = c_cb.scale[t] * v;
    }
}

extern "C" void kernel_launch(void* const* d_in, const int* in_sizes, int n_in,
                              void* d_out, int out_size, void* d_ws, size_t ws_size,
                              hipStream_t stream) {
    const float* pos = (const float*)d_in[0];
    float* out       = (float*)d_out;
    float* ws        = (float*)d_ws;
    const int n      = in_sizes[0] / 3;  // (N,3) flat -> N points

    // d_out is poisoned before every launch; ws holds the moment accumulators.
    hipMemsetAsync(d_out, 0, (size_t)out_size * sizeof(float), stream);
    hipMemsetAsync(d_ws, 0, WS_FLOATS * sizeof(float), stream);

    const int threads = 256;
    // R7's proven shape: 192 blocks/part x 4 parts = 768 = 3 blocks/CU.
    // (R8: 6 blocks/CU + split chains regressed 44 -> 52 us.)
    const int nblk_per_part = 192;
    const int blocks        = NPART * nblk_per_part;  // 768
    sht_kernel<<<blocks, threads, 0, stream>>>(pos, out, ws, n, nblk_per_part);
    sht_combine<<<1, 128, 0, stream>>>(ws, out);
}